// Round 9
// baseline (190.366 us; speedup 1.0000x reference)
//
#include <hip/hip_runtime.h>

// Problem constants (fixed by the reference's setup_inputs).
constexpr int N = 8192;          // row length
constexpr int K = 64;            // top-k
constexpr int THREADS = 256;     // 4 waves/block; grid 2048 = 8 blocks/CU -> ALL resident
constexpr int WAVES = THREADS / 64;
constexpr int EPT = N / THREADS; // 32 elements per thread
constexpr int VEC = EPT / 4;     // 8 float4 loads per thread per operand
constexpr int SEGCAP = 64;       // per-wave candidate segment (mean 29.3, sigma 5.4)
constexpr int CAP = 1024;        // fallback survivor buffer (4 KB)

// Pre-filter threshold. For N(0,1)+Gumbel rows of 8192:
// E[count(x >= t)] = 8192 * e^(0.5 - t); at t=4.75 -> 117 +- 10.8 per row,
// 29.3 +- 5.4 per wave-quarter. Rows where total not in [K,256] or any wave
// segment overflows take the exact full-radix fallback below.
constexpr float FTHRESH = 4.75f;

typedef float f32x4 __attribute__((ext_vector_type(4)));

// Map fp32 bits to an unsigned key with the same total order as float
// (fallback path only).
__device__ __forceinline__ unsigned orderable(float f) {
    unsigned x = __float_as_uint(f);
    return (x & 0x80000000u) ? ~x : (x | 0x80000000u);
}

// Barrier that does NOT drain vmcnt (LDS-communication barriers only).
__device__ __forceinline__ void barrier_nd() {
    asm volatile("s_waitcnt lgkmcnt(0)" ::: "memory");
    __builtin_amdgcn_s_barrier();
    asm volatile("" ::: "memory");
}

// (256,8): 64-VGPR budget. Live set: s[32] + ~16 staging + addr ~ 54. The
// load stream is deliberately chunked (2+2 float4) so the compiler never
// needs >16 staging regs. MLP proven irrelevant in R8 (all loads in flight
// at 36 VGPR changed nothing) -> optimize for context count instead:
// 8 blocks/CU x 4 waves = 32 waves/CU, 8 independent phase contexts.
__global__ __launch_bounds__(THREADS, 8)
void gumbel_topk_onehot(const float* __restrict__ logits,
                        const float* __restrict__ noise,
                        float* __restrict__ out)
{
    __shared__ __align__(16) unsigned hist[2048];       // 8 KB (fallback only)
    __shared__ __align__(16) unsigned cand[CAP];        // 4 KB (fallback only)
    __shared__ __align__(16) unsigned seg[WAVES][SEGCAP]; // 1 KB: per-wave candidates
    __shared__ unsigned scnt[WAVES];
    __shared__ unsigned wavesum[WAVES];
    __shared__ unsigned ccount;
    __shared__ unsigned sel_bin, sel_kth, sel_cnt;
    __shared__ unsigned r_val, r_take, r_ceq;

    const int tid  = threadIdx.x;
    const int lane = tid & 63;
    const int wave = tid >> 6;
    const long long row = blockIdx.x;

    // ---- Load row (chunked 2+2 float4: staging stays under 16 regs) ----
    const f32x4* l4 = (const f32x4*)(logits + row * (long long)N);
    const f32x4* n4 = (const f32x4*)(noise  + row * (long long)N);
    float s[EPT];
#pragma unroll
    for (int g4 = 0; g4 < VEC; g4 += 2) {
        f32x4 a0 = l4[tid + (g4 + 0) * THREADS];
        f32x4 a1 = l4[tid + (g4 + 1) * THREADS];
        f32x4 b0 = n4[tid + (g4 + 0) * THREADS];
        f32x4 b1 = n4[tid + (g4 + 1) * THREADS];
#pragma unroll
        for (int e = 0; e < 4; ++e) s[4 * g4 + e]     = a0[e] + b0[e];
#pragma unroll
        for (int e = 0; e < 4; ++e) s[4 * g4 + 4 + e] = a1[e] + b1[e];
    }

    // ---- Atomic-free compaction: ballot-prefix into wave-private segment ----
    // (R5's 16 dependent LDS atomicAdds = ~2k cy serial chain; this is pure
    // VALU + independent ds_writes, count stays in a register.)
    const unsigned long long below = (1ull << lane) - 1ull;
    unsigned cw = 0;
#pragma unroll
    for (int e = 0; e < EPT; ++e) {
        const bool p = (s[e] >= FTHRESH);
        const unsigned long long m = __ballot(p);
        if (p) {
            const unsigned pos = cw + (unsigned)__popcll(m & below);
            if (pos < (unsigned)SEGCAP) seg[wave][pos] = __float_as_uint(s[e]);
        }
        cw += (unsigned)__popcll(m);
    }
    if (lane == 0) scnt[wave] = cw;
    barrier_nd();                        // segments + counts visible

    const unsigned c0 = scnt[0], c1 = scnt[1], c2 = scnt[2], c3 = scnt[3];
    const unsigned c  = c0 + c1 + c2 + c3;
    const unsigned mx = max(max(c0, c1), max(c2, c3));
    const unsigned cws[WAVES] = {c0, c1, c2, c3};

    float Tf;                            // K-th largest value (as float)
    unsigned take_eq, c_eq;
    bool fast;

    if (c >= (unsigned)K && c <= (unsigned)THREADS && mx <= (unsigned)SEGCAP) {
        // ======== Common path: exact rank-count over segmented candidates ====
        // All candidates positive -> uint bit compare == float compare.
        const bool have = (tid < (int)c);
        unsigned myv = 0u;
        if (have) {                      // locate my dense index in segments
            unsigned d = (unsigned)tid, w2 = 0;
            if (d >= c0) { d -= c0; w2 = 1;
                if (d >= c1) { d -= c1; w2 = 2;
                    if (d >= c2) { d -= c2; w2 = 3; } } }
            myv = seg[w2][d];
        }
        if (tid < (int)((c + 63u) & ~63u)) {   // ~2 waves participate (uniform)
            unsigned g = 0, eq = 0;
#pragma unroll
            for (int w2 = 0; w2 < WAVES; ++w2) {
                const unsigned cn = cws[w2];
                const uint4* s4 = (const uint4*)seg[w2];
                for (unsigned q = 0; q * 4 < cn; ++q) {
                    const uint4 v = s4[q];         // 16B LDS broadcast
                    const unsigned i0 = q * 4;
                    if (i0 + 0 < cn) { g += v.x > myv; eq += v.x == myv; }
                    if (i0 + 1 < cn) { g += v.y > myv; eq += v.y == myv; }
                    if (i0 + 2 < cn) { g += v.z > myv; eq += v.z == myv; }
                    if (i0 + 3 < cn) { g += v.w > myv; eq += v.w == myv; }
                }
            }
            // K-th largest = unique value with g < K <= g+eq (dup holders agree).
            if (have && g < (unsigned)K && g + eq >= (unsigned)K) {
                r_val  = myv;
                r_take = (unsigned)K - g;
                r_ceq  = eq;
            }
        }
        barrier_nd();
        Tf      = __uint_as_float(r_val);
        take_eq = r_take;
        c_eq    = r_ceq;
        fast    = (take_eq == c_eq);
    } else {
        // ======== Rare fallback: exact 3-round radix select (any input) ========
        unsigned kth = K;

#define SELECT_BIN(BPT)                                                      \
        {                                                                    \
            unsigned p = 0;                                                  \
            _Pragma("unroll")                                                \
            for (int j = 0; j < (BPT); ++j) p += hist[tid * (BPT) + j];      \
            unsigned sc = p;                                                 \
            _Pragma("unroll")                                                \
            for (int off = 1; off < 64; off <<= 1) {                         \
                unsigned v = __shfl_down(sc, off);                           \
                if (lane + off < 64) sc += v;                                \
            }                                                                \
            if (lane == 0) wavesum[wave] = sc;                               \
            __syncthreads();                                                 \
            unsigned S = sc;                                                 \
            _Pragma("unroll")                                                \
            for (int w = 0; w < WAVES; ++w) if (w > wave) S += wavesum[w];   \
            unsigned Snext = S - p;                                          \
            if (S >= kth && Snext < kth) {                                   \
                unsigned cum = Snext;                                        \
                for (int j = (BPT) - 1; j >= 0; --j) {                       \
                    unsigned b = tid * (BPT) + j;                            \
                    unsigned cc = hist[b];                                   \
                    if (cum + cc >= kth) {                                   \
                        sel_bin = b;                                         \
                        sel_kth = kth - cum;                                 \
                        sel_cnt = cc;                                        \
                        break;                                               \
                    }                                                        \
                    cum += cc;                                               \
                }                                                            \
            }                                                                \
            __syncthreads();                                                 \
        }

        // Round 1: bits [31:21] of orderable keys (2048 bins, BPT=8)
        for (int i = tid; i < 512; i += THREADS)
            ((uint4*)hist)[i] = make_uint4(0u, 0u, 0u, 0u);
        if (tid == 0) ccount = 0u;
        __syncthreads();
#pragma unroll
        for (int e = 0; e < EPT; ++e)
            atomicAdd(&hist[orderable(s[e]) >> 21], 1u);
        __syncthreads();
        SELECT_BIN(8)
        const unsigned b1   = sel_bin;
        const unsigned cnt1 = sel_cnt;
        kth = sel_kth;

        // Compact round-1 survivors (low 21 bits)
#pragma unroll
        for (int e = 0; e < EPT; ++e) {
            const unsigned k_e = orderable(s[e]);
            if ((k_e >> 21) == b1) {
                const unsigned pos = atomicAdd(&ccount, 1u);
                if (pos < (unsigned)CAP) cand[pos] = k_e & 0x1FFFFFu;
            }
        }
        __syncthreads();
        const bool use_cand = (cnt1 <= (unsigned)CAP);

        // Round 2: bits [20:10] (2048 bins, BPT=8)
        for (int i = tid; i < 512; i += THREADS)
            ((uint4*)hist)[i] = make_uint4(0u, 0u, 0u, 0u);
        __syncthreads();
        if (use_cand) {
            for (int i = tid; i < (int)cnt1; i += THREADS)
                atomicAdd(&hist[cand[i] >> 10], 1u);
        } else {
#pragma unroll
            for (int e = 0; e < EPT; ++e) {
                const unsigned k_e = orderable(s[e]);
                if ((k_e >> 21) == b1)
                    atomicAdd(&hist[(k_e >> 10) & 0x7FFu], 1u);
            }
        }
        __syncthreads();
        SELECT_BIN(8)
        const unsigned b2 = sel_bin;
        kth = sel_kth;
        __syncthreads();

        // Round 3: bits [9:0] (1024 bins, BPT=4)
        for (int i = tid; i < 256; i += THREADS)
            ((uint4*)hist)[i] = make_uint4(0u, 0u, 0u, 0u);
        __syncthreads();
        if (use_cand) {
            for (int i = tid; i < (int)cnt1; i += THREADS) {
                const unsigned cv = cand[i];
                if ((cv >> 10) == b2) atomicAdd(&hist[cv & 0x3FFu], 1u);
            }
        } else {
            const unsigned pfx = (b1 << 11) | b2;
#pragma unroll
            for (int e = 0; e < EPT; ++e) {
                const unsigned k_e = orderable(s[e]);
                if ((k_e >> 10) == pfx)
                    atomicAdd(&hist[k_e & 0x3FFu], 1u);
            }
        }
        __syncthreads();
        SELECT_BIN(4)
        const unsigned T_ord = (b1 << 21) | (b2 << 10) | sel_bin;
        // Invert orderable(): high bit set -> nonnegative float, else negative.
        const unsigned bits = (T_ord & 0x80000000u) ? (T_ord & 0x7FFFFFFFu)
                                                    : ~T_ord;
        Tf      = __uint_as_float(bits);
        take_eq = sel_kth;
        c_eq    = sel_cnt;
        fast    = (take_eq == c_eq);
#undef SELECT_BIN
    }

    // ---- Write one-hot output from registers (plain stores: complete at
    //      L2 latency; nt proved traffic-neutral in R1-R8 counters) ----
    f32x4* orow = (f32x4*)(out + row * (long long)N);
    if (fast) {
#pragma unroll
        for (int i = 0; i < VEC; ++i) {
            f32x4 o;
            o.x = (s[4*i+0] >= Tf) ? 1.0f : 0.0f;
            o.y = (s[4*i+1] >= Tf) ? 1.0f : 0.0f;
            o.z = (s[4*i+2] >= Tf) ? 1.0f : 0.0f;
            o.w = (s[4*i+3] >= Tf) ? 1.0f : 0.0f;
            orow[tid + i * THREADS] = o;
        }
    } else {
#pragma unroll
        for (int i = 0; i < VEC; ++i) {
            f32x4 o;
            o.x = (s[4*i+0] > Tf) ? 1.0f : 0.0f;
            o.y = (s[4*i+1] > Tf) ? 1.0f : 0.0f;
            o.z = (s[4*i+2] > Tf) ? 1.0f : 0.0f;
            o.w = (s[4*i+3] > Tf) ? 1.0f : 0.0f;
            orow[tid + i * THREADS] = o;
        }
        // Tie group straddles the boundary — lowest indices win
        // (jax.lax.top_k semantics). Recompute serially from global.
        __syncthreads();   // full drain: one-hot stores done before rewrite
        if (tid == 0) {
            const float* lf = logits + row * (long long)N;
            const float* nf = noise  + row * (long long)N;
            float* of = out + row * (long long)N;
            unsigned cc = 0;
            for (int i = 0; i < N; ++i) {
                if (lf[i] + nf[i] == Tf) {
                    of[i] = 1.0f;
                    if (++cc == take_eq) break;
                }
            }
        }
    }
}

extern "C" void kernel_launch(void* const* d_in, const int* in_sizes, int n_in,
                              void* d_out, int out_size, void* d_ws, size_t ws_size,
                              hipStream_t stream) {
    const float* logits = (const float*)d_in[0];
    const float* noise  = (const float*)d_in[1];
    float* out = (float*)d_out;
    const int rows = in_sizes[0] / N;   // 2048
    gumbel_topk_onehot<<<rows, THREADS, 0, stream>>>(logits, noise, out);
}

// Round 10
// 185.601 us; speedup vs baseline: 1.0257x; 1.0257x over previous
//
#include <hip/hip_runtime.h>

// Problem constants (fixed by the reference's setup_inputs).
constexpr int N = 8192;          // row length
constexpr int K = 64;            // top-k
constexpr int THREADS = 256;     // 4 waves/block; grid 2048 = 8 blocks/CU, all resident
constexpr int WAVES = THREADS / 64;
constexpr int F4PT = (N / 4) / THREADS;   // 8 float4 per thread per operand
constexpr int SEGCAP = 64;       // per-wave candidate segment (mean 29.3, sigma 5.4)

// Pre-filter threshold. For N(0,1)+Gumbel rows of 8192:
// E[count(x >= t)] = 8192 * e^(0.5 - t); at t=4.75 -> 117 +- 10.8 per row,
// 29.3 +- 5.4 per wave-quarter. P(any wave segment > 64) ~ 1e-10.
// Rows violating the guards take the exact radix fallback (re-reads the row),
// so this is a speed hint, not a correctness assumption.
constexpr float FTHRESH = 4.75f;

typedef float f32x4 __attribute__((ext_vector_type(4)));

// Map fp32 bits to an unsigned key with the same total order as float
// (fallback path only).
__device__ __forceinline__ unsigned orderable(float f) {
    unsigned x = __float_as_uint(f);
    return (x & 0x80000000u) ? ~x : (x | 0x80000000u);
}

// Barrier that does NOT drain vmcnt (LDS-communication barriers only).
__device__ __forceinline__ void barrier_nd() {
    asm volatile("s_waitcnt lgkmcnt(0)" ::: "memory");
    __builtin_amdgcn_s_barrier();
    asm volatile("" ::: "memory");
}

// (256,8): 64-VGPR budget. R9 spilled because s[32] had to survive the middle
// phases for the final compare. Here NO row-sized state survives: the one-hot
// is zeros (fused into the load pass) + a ~64-element scatter from (val,idx)
// candidates. Live set ~30 VGPRs -> no spill at 8 blocks/CU.
__global__ __launch_bounds__(THREADS, 8)
void gumbel_topk_onehot(const float* __restrict__ logits,
                        const float* __restrict__ noise,
                        float* __restrict__ out)
{
    __shared__ __align__(16) unsigned hist[2048];         // 8 KB (fallback only)
    __shared__ __align__(16) float    segv[WAVES][SEGCAP];// 1 KB: candidate values
    __shared__ __align__(16) unsigned segi[WAVES][SEGCAP];// 1 KB: candidate indices
    __shared__ unsigned scnt[WAVES];
    __shared__ unsigned wavesum[WAVES];
    __shared__ unsigned sel_bin, sel_kth, sel_cnt;
    __shared__ float    sh_T;
    __shared__ unsigned sh_take, sh_ceq;

    const int tid  = threadIdx.x;
    const int lane = tid & 63;
    const int wave = tid >> 6;
    const long long row = blockIdx.x;

    const f32x4* l4 = (const f32x4*)(logits + row * (long long)N);
    const f32x4* n4 = (const f32x4*)(noise  + row * (long long)N);
    f32x4*       o4 = (f32x4*)(out + row * (long long)N);
    float*     orow = out + row * (long long)N;

    const unsigned long long below = (1ull << lane) - 1ull;
    const f32x4 zero4 = {0.f, 0.f, 0.f, 0.f};

    // ======== Single streaming pass: load + zero-store + compact ========
    // Zero stores depend on nothing -> issue immediately, overlap the loads.
    // Candidates (val,idx) go to wave-private segments via ballot prefix
    // (no atomics; count cw stays in a register, wave-uniform).
    unsigned cw = 0;
#pragma unroll
    for (int g = 0; g < F4PT; g += 2) {
        f32x4 a0 = l4[tid + (g + 0) * THREADS];
        f32x4 a1 = l4[tid + (g + 1) * THREADS];
        f32x4 b0 = n4[tid + (g + 0) * THREADS];
        f32x4 b1 = n4[tid + (g + 1) * THREADS];
        o4[tid + (g + 0) * THREADS] = zero4;
        o4[tid + (g + 1) * THREADS] = zero4;
        float sv[8];
#pragma unroll
        for (int e = 0; e < 4; ++e) { sv[e] = a0[e] + b0[e]; sv[4 + e] = a1[e] + b1[e]; }
        const unsigned i0 = 4u * (unsigned)(tid + (g + 0) * THREADS);
        const unsigned i1 = 4u * (unsigned)(tid + (g + 1) * THREADS);
#pragma unroll
        for (int e = 0; e < 8; ++e) {
            const bool p = (sv[e] >= FTHRESH);
            const unsigned long long m = __ballot(p);
            if (p) {
                const unsigned pos = cw + (unsigned)__popcll(m & below);
                if (pos < (unsigned)SEGCAP) {
                    segv[wave][pos] = sv[e];
                    segi[wave][pos] = (e < 4) ? (i0 + e) : (i1 + e - 4);
                }
            }
            cw += (unsigned)__popcll(m);
        }
    }
    if (lane == 0) scnt[wave] = cw;
    barrier_nd();                        // segments + counts visible (LDS only)

    const unsigned c0 = scnt[0], c1 = scnt[1], c2 = scnt[2], c3 = scnt[3];
    const unsigned c  = c0 + c1 + c2 + c3;
    const unsigned mx = max(max(c0, c1), max(c2, c3));

    if (c >= (unsigned)K && mx <= (unsigned)SEGCAP) {
        // ======== Common path: rank-count over <=256 segmented candidates ====
        const unsigned cws[WAVES] = {c0, c1, c2, c3};
        const bool have = ((unsigned)tid < c);
        float myv = 0.f; unsigned myi = 0;
        if (have) {                      // dense index -> (wave segment, slot)
            unsigned d = (unsigned)tid, w2 = 0;
            if (d >= c0) { d -= c0; w2 = 1;
                if (d >= c1) { d -= c1; w2 = 2;
                    if (d >= c2) { d -= c2; w2 = 3; } } }
            myv = segv[w2][d]; myi = segi[w2][d];
        }
        if ((unsigned)tid < ((c + 63u) & ~63u)) {    // idle waves skip (uniform)
            unsigned g = 0, eq = 0;
#pragma unroll
            for (int w2 = 0; w2 < WAVES; ++w2) {
                const unsigned cn = cws[w2];
                const f32x4* s4 = (const f32x4*)segv[w2];
                for (unsigned q = 0; q * 4 < cn; ++q) {
                    const f32x4 v = s4[q];           // 16B LDS broadcast
                    const unsigned b = q * 4;
                    if (b + 0 < cn) { g += v.x > myv; eq += v.x == myv; }
                    if (b + 1 < cn) { g += v.y > myv; eq += v.y == myv; }
                    if (b + 2 < cn) { g += v.z > myv; eq += v.z == myv; }
                    if (b + 3 < cn) { g += v.w > myv; eq += v.w == myv; }
                }
            }
            // K-th largest = unique value with g < K <= g+eq (dup holders agree).
            if (have && g < (unsigned)K && g + eq >= (unsigned)K) {
                sh_T = myv; sh_take = (unsigned)K - g; sh_ceq = eq;
            }
        }
        barrier_nd();
        const float Tf = sh_T;
        const unsigned take_eq = sh_take;
        const bool fast = (take_eq == sh_ceq);

        // All zero-stores must land before the ones-scatter (different threads
        // may own the scattered addresses): block-wide vmcnt drain + barrier.
        asm volatile("s_waitcnt vmcnt(0)" ::: "memory");
        __builtin_amdgcn_s_barrier();

        if (have) {
            if (myv > Tf || (fast && myv == Tf)) {
                orow[myi] = 1.0f;
            } else if (!fast && myv == Tf) {
                // Tie straddles boundary: lowest indices win (jax.lax.top_k).
                unsigned r = 0;
#pragma unroll
                for (int w2 = 0; w2 < WAVES; ++w2) {
                    const unsigned cn = cws[w2];
                    for (unsigned q = 0; q < cn; ++q)
                        r += (segv[w2][q] == Tf) && (segi[w2][q] < myi);
                }
                if (r < take_eq) orow[myi] = 1.0f;
            }
        }
    } else {
        // ======== Rare fallback: exact 3-round radix, re-reading the row ======
        unsigned kth = K;

#define SELECT_BIN(BPT)                                                      \
        {                                                                    \
            unsigned p = 0;                                                  \
            _Pragma("unroll")                                                \
            for (int j = 0; j < (BPT); ++j) p += hist[tid * (BPT) + j];      \
            unsigned sc = p;                                                 \
            _Pragma("unroll")                                                \
            for (int off = 1; off < 64; off <<= 1) {                         \
                unsigned v = __shfl_down(sc, off);                           \
                if (lane + off < 64) sc += v;                                \
            }                                                                \
            if (lane == 0) wavesum[wave] = sc;                               \
            __syncthreads();                                                 \
            unsigned S = sc;                                                 \
            _Pragma("unroll")                                                \
            for (int w = 0; w < WAVES; ++w) if (w > wave) S += wavesum[w];   \
            unsigned Snext = S - p;                                          \
            if (S >= kth && Snext < kth) {                                   \
                unsigned cum = Snext;                                        \
                for (int j = (BPT) - 1; j >= 0; --j) {                       \
                    unsigned b = tid * (BPT) + j;                            \
                    unsigned cc = hist[b];                                   \
                    if (cum + cc >= kth) {                                   \
                        sel_bin = b;                                         \
                        sel_kth = kth - cum;                                 \
                        sel_cnt = cc;                                        \
                        break;                                               \
                    }                                                        \
                    cum += cc;                                               \
                }                                                            \
            }                                                                \
            __syncthreads();                                                 \
        }

        // Round 1: bits [31:21] (2048 bins, BPT=8)
        for (int i = tid; i < 512; i += THREADS)
            ((uint4*)hist)[i] = make_uint4(0u, 0u, 0u, 0u);
        __syncthreads();   // also drains vmcnt: zero-stores complete
        for (int g = 0; g < F4PT; ++g) {
            f32x4 a = l4[tid + g * THREADS];
            f32x4 b = n4[tid + g * THREADS];
#pragma unroll
            for (int e = 0; e < 4; ++e)
                atomicAdd(&hist[orderable(a[e] + b[e]) >> 21], 1u);
        }
        __syncthreads();
        SELECT_BIN(8)
        const unsigned b1 = sel_bin;
        kth = sel_kth;

        // Round 2: bits [20:10] (2048 bins, BPT=8)
        for (int i = tid; i < 512; i += THREADS)
            ((uint4*)hist)[i] = make_uint4(0u, 0u, 0u, 0u);
        __syncthreads();
        for (int g = 0; g < F4PT; ++g) {
            f32x4 a = l4[tid + g * THREADS];
            f32x4 b = n4[tid + g * THREADS];
#pragma unroll
            for (int e = 0; e < 4; ++e) {
                const unsigned k_e = orderable(a[e] + b[e]);
                if ((k_e >> 21) == b1)
                    atomicAdd(&hist[(k_e >> 10) & 0x7FFu], 1u);
            }
        }
        __syncthreads();
        SELECT_BIN(8)
        const unsigned b2 = sel_bin;
        kth = sel_kth;

        // Round 3: bits [9:0] (1024 bins, BPT=4)
        for (int i = tid; i < 256; i += THREADS)
            ((uint4*)hist)[i] = make_uint4(0u, 0u, 0u, 0u);
        __syncthreads();
        const unsigned pfx = (b1 << 11) | b2;
        for (int g = 0; g < F4PT; ++g) {
            f32x4 a = l4[tid + g * THREADS];
            f32x4 b = n4[tid + g * THREADS];
#pragma unroll
            for (int e = 0; e < 4; ++e) {
                const unsigned k_e = orderable(a[e] + b[e]);
                if ((k_e >> 10) == pfx)
                    atomicAdd(&hist[k_e & 0x3FFu], 1u);
            }
        }
        __syncthreads();
        SELECT_BIN(4)
        const unsigned T_ord   = (b1 << 21) | (b2 << 10) | sel_bin;
        const unsigned take_eq = sel_kth;
        const bool fast = (take_eq == sel_cnt);
#undef SELECT_BIN

        // Rewrite the full one-hot row (over the zeros; vmcnt was drained by
        // the __syncthreads above, and each address has a single writer).
        for (int g = 0; g < F4PT; ++g) {
            f32x4 a = l4[tid + g * THREADS];
            f32x4 b = n4[tid + g * THREADS];
            f32x4 o;
#pragma unroll
            for (int e = 0; e < 4; ++e) {
                const unsigned k_e = orderable(a[e] + b[e]);
                o[e] = (k_e > T_ord || (fast && k_e == T_ord)) ? 1.0f : 0.0f;
            }
            o4[tid + g * THREADS] = o;
        }
        if (!fast) {
            // Tie straddles boundary: lowest indices win. Serial exact fix.
            __syncthreads();   // drain: rewrite stores done before corrections
            if (tid == 0) {
                const float* lf = logits + row * (long long)N;
                const float* nf = noise  + row * (long long)N;
                unsigned cc = 0;
                for (int i = 0; i < N; ++i) {
                    if (orderable(lf[i] + nf[i]) == T_ord) {
                        orow[i] = 1.0f;
                        if (++cc == take_eq) break;
                    }
                }
            }
        }
    }
}

extern "C" void kernel_launch(void* const* d_in, const int* in_sizes, int n_in,
                              void* d_out, int out_size, void* d_ws, size_t ws_size,
                              hipStream_t stream) {
    const float* logits = (const float*)d_in[0];
    const float* noise  = (const float*)d_in[1];
    float* out = (float*)d_out;
    const int rows = in_sizes[0] / N;   // 2048
    gumbel_topk_onehot<<<rows, THREADS, 0, stream>>>(logits, noise, out);
}